// Round 1
// baseline (235.398 us; speedup 1.0000x reference)
//
#include <hip/hip_runtime.h>
#include <hip/hip_bf16.h>

#define NN 8192
#define CC 256
#define CQK 32

using bf16x8 = __attribute__((ext_vector_type(8))) short;
using f32x4  = __attribute__((ext_vector_type(4))) float;

static __device__ __forceinline__ unsigned short f2bf(float x) {
    union { __hip_bfloat16 h; unsigned short u; } cv;
    cv.h = __float2bfloat16(x);
    return cv.u;
}
static __device__ __forceinline__ float bf2f(unsigned short u) {
    union { unsigned short u; __hip_bfloat16 h; } cv;
    cv.u = u;
    return __bfloat162float(cv.h);
}

// ---------------------------------------------------------------------------
// Kernel 1: projections.  q = f @ Wqk^T (stored as hi/lo bf16 split),
//           v = f @ Wv^T + bv (stored transposed as vT[c][n] bf16).
// grid 512 blocks x 256 thr; each block does 16 rows of f.
// ---------------------------------------------------------------------------
__global__ __launch_bounds__(256) void proj_kernel(
    const float* __restrict__ f, const float* __restrict__ Wqk,
    const float* __restrict__ Wv, const float* __restrict__ bv,
    unsigned short* __restrict__ qhi, unsigned short* __restrict__ qlo,
    unsigned short* __restrict__ vT)
{
    __shared__ __align__(16) float fl[16][CC];
    const int t  = threadIdx.x;
    const int r0 = blockIdx.x * 16;

    {   // stage f tile (16 x 256 f32) as float4
        const float4* src = (const float4*)(f + (size_t)r0 * CC);
        float4* dst = (float4*)&fl[0][0];
#pragma unroll
        for (int it = 0; it < 4; ++it) dst[t + 256 * it] = src[t + 256 * it];
    }
    __syncthreads();

    {   // v column c = t for all 16 rows
        float acc[16];
#pragma unroll
        for (int r = 0; r < 16; ++r) acc[r] = 0.f;
        const float4* w4 = (const float4*)(Wv + (size_t)t * CC);
        for (int k4 = 0; k4 < 64; ++k4) {
            float4 wv = w4[k4];
#pragma unroll
            for (int r = 0; r < 16; ++r) {
                float4 fv = *(const float4*)&fl[r][k4 * 4];
                acc[r] += wv.x * fv.x + wv.y * fv.y + wv.z * fv.z + wv.w * fv.w;
            }
        }
        float b = bv[t];
#pragma unroll
        for (int r = 0; r < 16; ++r)
            vT[(size_t)t * NN + (r0 + r)] = f2bf(acc[r] + b);
    }

    {   // q: thread t -> cq = t&31, rows (t>>5)*2, (t>>5)*2+1
        const int cq = t & 31;
        const int rg = t >> 5;
        const int ra = rg * 2, rb = rg * 2 + 1;
        const float4* w4 = (const float4*)(Wqk + (size_t)cq * CC);
        float a0 = 0.f, a1 = 0.f;
        for (int k4 = 0; k4 < 64; ++k4) {
            float4 wq = w4[k4];
            float4 f0 = *(const float4*)&fl[ra][k4 * 4];
            float4 f1 = *(const float4*)&fl[rb][k4 * 4];
            a0 += wq.x * f0.x + wq.y * f0.y + wq.z * f0.z + wq.w * f0.w;
            a1 += wq.x * f1.x + wq.y * f1.y + wq.z * f1.z + wq.w * f1.w;
        }
        unsigned short h0 = f2bf(a0);
        unsigned short l0 = f2bf(a0 - bf2f(h0));
        unsigned short h1 = f2bf(a1);
        unsigned short l1 = f2bf(a1 - bf2f(h1));
        qhi[(size_t)(r0 + ra) * CQK + cq] = h0;
        qlo[(size_t)(r0 + ra) * CQK + cq] = l0;
        qhi[(size_t)(r0 + rb) * CQK + cq] = h1;
        qlo[(size_t)(r0 + rb) * CQK + cq] = l1;
    }
}

// ---------------------------------------------------------------------------
// Kernel 2: per-row softmax stats. m[i] = max_j e_ij, linv[i] = 1/sum_j exp(e-m).
// e via hi/lo bf16 MFMA (16x16x32). grid 256 x 512 thr (8 waves);
// block owns 32 i-rows, sweeps j in steps of 128 (16 j per wave).
// ---------------------------------------------------------------------------
__global__ __launch_bounds__(512) void pass1_kernel(
    const unsigned short* __restrict__ qhi,
    const unsigned short* __restrict__ qlo,
    float* __restrict__ mrow, float* __restrict__ linvrow)
{
    const int t    = threadIdx.x;
    const int lane = t & 63;
    const int w    = t >> 6;        // 0..7
    const int lr   = lane & 15;
    const int lc   = lane >> 4;     // k-chunk 0..3
    const int i0   = blockIdx.x * 32;

    bf16x8 ahi[2], alo[2];
#pragma unroll
    for (int f_ = 0; f_ < 2; ++f_) {
        int row = i0 + 16 * f_ + lr;
        ahi[f_] = *(const bf16x8*)(qhi + (size_t)row * CQK + 8 * lc);
        alo[f_] = *(const bf16x8*)(qlo + (size_t)row * CQK + 8 * lc);
    }

    float m_run[8], s_run[8];
#pragma unroll
    for (int k = 0; k < 8; ++k) { m_run[k] = -INFINITY; s_run[k] = 0.f; }

    int jc = 16 * w + lr;
    bf16x8 bhi = *(const bf16x8*)(qhi + (size_t)jc * CQK + 8 * lc);
    bf16x8 blo = *(const bf16x8*)(qlo + (size_t)jc * CQK + 8 * lc);

    for (int j0 = 0; j0 < NN; j0 += 128) {
        // prefetch next window (clamped; last iter harmlessly reloads)
        int jn = min(j0 + 128 + 16 * w + lr, NN - 1);
        bf16x8 nbhi = *(const bf16x8*)(qhi + (size_t)jn * CQK + 8 * lc);
        bf16x8 nblo = *(const bf16x8*)(qlo + (size_t)jn * CQK + 8 * lc);
#pragma unroll
        for (int f_ = 0; f_ < 2; ++f_) {
            f32x4 e = {0.f, 0.f, 0.f, 0.f};
            e = __builtin_amdgcn_mfma_f32_16x16x32_bf16(ahi[f_], bhi, e, 0, 0, 0);
            e = __builtin_amdgcn_mfma_f32_16x16x32_bf16(ahi[f_], blo, e, 0, 0, 0);
            e = __builtin_amdgcn_mfma_f32_16x16x32_bf16(alo[f_], bhi, e, 0, 0, 0);
#pragma unroll
            for (int r = 0; r < 4; ++r) {
                int k = f_ * 4 + r;
                float ev = e[r];
                float mo = m_run[k];
                float mn = fmaxf(mo, ev);
                float s  = s_run[k];
                s = (mn > mo) ? s * __expf(mo - mn) : s;
                s_run[k] = s + __expf(ev - mn);
                m_run[k] = mn;
            }
        }
        bhi = nbhi; blo = nblo;
    }

    // butterfly over the 16 j-lanes (lanes sharing lane>>4 hold same rows)
#pragma unroll
    for (int off = 1; off < 16; off <<= 1) {
#pragma unroll
        for (int k = 0; k < 8; ++k) {
            float mo = __shfl_xor(m_run[k], off);
            float so = __shfl_xor(s_run[k], off);
            float mn = fmaxf(m_run[k], mo);
            s_run[k] = s_run[k] * __expf(m_run[k] - mn) + so * __expf(mo - mn);
            m_run[k] = mn;
        }
    }

    __shared__ float red_m[8][32];
    __shared__ float red_s[8][32];
    if (lr == 0) {
#pragma unroll
        for (int f_ = 0; f_ < 2; ++f_)
#pragma unroll
            for (int r = 0; r < 4; ++r) {
                int row = 16 * f_ + 4 * lc + r;
                red_m[w][row] = m_run[f_ * 4 + r];
                red_s[w][row] = s_run[f_ * 4 + r];
            }
    }
    __syncthreads();
    if (t < 32) {
        float mf = red_m[0][t];
#pragma unroll
        for (int ww = 1; ww < 8; ++ww) mf = fmaxf(mf, red_m[ww][t]);
        float sf = 0.f;
#pragma unroll
        for (int ww = 0; ww < 8; ++ww) sf += red_s[ww][t] * __expf(red_m[ww][t] - mf);
        mrow[i0 + t]    = mf;
        linvrow[i0 + t] = 1.0f / sf;
    }
}

// ---------------------------------------------------------------------------
// Kernel 3: out[j,c] = gamma * sum_i exp(e_ij - m_i)*linv_i * v[i,c] + f[j,c]
// grid 256 x 512 thr (8 waves). Block: 32 j-rows, full C=256, i-step 64.
// Wave w: E-tile (jf=w&1, i-window 16*(w>>1)); PV columns c in [32w,32w+32).
// P goes through padded LDS (row stride 72 u16 = 144B -> <=2-way conflicts).
// ---------------------------------------------------------------------------
__global__ __launch_bounds__(512) void pass2_kernel(
    const unsigned short* __restrict__ qhi,
    const unsigned short* __restrict__ qlo,
    const unsigned short* __restrict__ vT,
    const float* __restrict__ mrow,
    const float* __restrict__ linvrow,
    const float* __restrict__ f,
    const float* __restrict__ gammap,
    float* __restrict__ out)
{
    __shared__ __align__(16) unsigned short p_lds[32][72];
    const int t    = threadIdx.x;
    const int lane = t & 63;
    const int w    = t >> 6;          // 0..7
    const int lr   = lane & 15;
    const int lc   = lane >> 4;
    const int j0   = blockIdx.x * 32;
    const int jf   = w & 1;           // this wave's E-tile j half
    const int iw   = 16 * (w >> 1);   // this wave's E i-window

    bf16x8 ajhi, ajlo;
    {
        int row = j0 + 16 * jf + lr;
        ajhi = *(const bf16x8*)(qhi + (size_t)row * CQK + 8 * lc);
        ajlo = *(const bf16x8*)(qlo + (size_t)row * CQK + 8 * lc);
    }

    f32x4 acc[2][2];
    {
        f32x4 z = {0.f, 0.f, 0.f, 0.f};
        acc[0][0] = z; acc[0][1] = z; acc[1][0] = z; acc[1][1] = z;
    }

    int ic = iw + lr;
    bf16x8 bhi = *(const bf16x8*)(qhi + (size_t)ic * CQK + 8 * lc);
    bf16x8 blo = *(const bf16x8*)(qlo + (size_t)ic * CQK + 8 * lc);
    float mi = mrow[ic];
    float li = linvrow[ic];

    for (int i0s = 0; i0s < NN; i0s += 64) {
        // prefetch next-step E operands + stats (clamped)
        int icn = min(i0s + 64 + iw + lr, NN - 1);
        bf16x8 nbhi = *(const bf16x8*)(qhi + (size_t)icn * CQK + 8 * lc);
        bf16x8 nblo = *(const bf16x8*)(qlo + (size_t)icn * CQK + 8 * lc);
        float  nmi  = mrow[icn];
        float  nli  = linvrow[icn];

        // prefetch this step's V fragments (independent of p)
        bf16x8 bv8[2][2];
#pragma unroll
        for (int ks = 0; ks < 2; ++ks)
#pragma unroll
            for (int cf = 0; cf < 2; ++cf) {
                int cc = 32 * w + 16 * cf + lr;
                bv8[ks][cf] = *(const bf16x8*)(vT + (size_t)cc * NN + i0s + 32 * ks + 8 * lc);
            }

        // E tile: e[j, i] = q_j . q_i  (hi/lo split, fp32 accum)
        f32x4 ee = {0.f, 0.f, 0.f, 0.f};
        ee = __builtin_amdgcn_mfma_f32_16x16x32_bf16(ajhi, bhi, ee, 0, 0, 0);
        ee = __builtin_amdgcn_mfma_f32_16x16x32_bf16(ajhi, blo, ee, 0, 0, 0);
        ee = __builtin_amdgcn_mfma_f32_16x16x32_bf16(ajlo, bhi, ee, 0, 0, 0);

        __syncthreads();   // previous step's PV reads are done
#pragma unroll
        for (int r = 0; r < 4; ++r) {
            float p = __expf(ee[r] - mi) * li;
            p_lds[16 * jf + 4 * lc + r][iw + lr] = f2bf(p);
        }
        __syncthreads();   // p tile complete

        // PV: acc[jp][cf] += P[32j x 32i] @ V[32i x 16c]
#pragma unroll
        for (int ks = 0; ks < 2; ++ks) {
            bf16x8 pa[2];
#pragma unroll
            for (int jp = 0; jp < 2; ++jp)
                pa[jp] = *(const bf16x8*)&p_lds[16 * jp + lr][32 * ks + 8 * lc];
#pragma unroll
            for (int cf = 0; cf < 2; ++cf)
#pragma unroll
                for (int jp = 0; jp < 2; ++jp)
                    acc[jp][cf] = __builtin_amdgcn_mfma_f32_16x16x32_bf16(
                        pa[jp], bv8[ks][cf], acc[jp][cf], 0, 0, 0);
        }

        bhi = nbhi; blo = nblo; mi = nmi; li = nli;
    }

    float g = gammap[0];
#pragma unroll
    for (int jp = 0; jp < 2; ++jp)
#pragma unroll
        for (int cf = 0; cf < 2; ++cf)
#pragma unroll
            for (int r = 0; r < 4; ++r) {
                int j = j0 + 16 * jp + 4 * lc + r;
                int c = 32 * w + 16 * cf + lr;
                out[(size_t)j * CC + c] = g * acc[jp][cf][r] + f[(size_t)j * CC + c];
            }
}

// ---------------------------------------------------------------------------
extern "C" void kernel_launch(void* const* d_in, const int* in_sizes, int n_in,
                              void* d_out, int out_size, void* d_ws, size_t ws_size,
                              hipStream_t stream) {
    const float* f     = (const float*)d_in[0];
    const float* Wqk   = (const float*)d_in[1];
    const float* Wv    = (const float*)d_in[2];
    const float* bv    = (const float*)d_in[3];
    const float* gamma = (const float*)d_in[4];
    float* out = (float*)d_out;

    char* ws = (char*)d_ws;
    unsigned short* qhi = (unsigned short*)(ws);                      // 512 KB
    unsigned short* qlo = (unsigned short*)(ws + (512 << 10));        // 512 KB
    unsigned short* vT  = (unsigned short*)(ws + (1 << 20));          // 4 MB
    float* mrow = (float*)(ws + (5 << 20));                           // 32 KB
    float* linv = (float*)(ws + (5 << 20) + (32 << 10));              // 32 KB

    proj_kernel<<<dim3(NN / 16), dim3(256), 0, stream>>>(f, Wqk, Wv, bv, qhi, qlo, vT);
    pass1_kernel<<<dim3(NN / 32), dim3(512), 0, stream>>>(qhi, qlo, mrow, linv);
    pass2_kernel<<<dim3(NN / 32), dim3(512), 0, stream>>>(qhi, qlo, vT, mrow, linv, f, gamma, out);
}